// Round 4
// baseline (1371.349 us; speedup 1.0000x reference)
//
#include <hip/hip_runtime.h>

#define NEG_SLOPE 0.2f

__device__ __forceinline__ float wave_sum64(float v) {
#pragma unroll
    for (int off = 32; off >= 1; off >>= 1) v += __shfl_xor(v, off, 64);
    return v;
}

// ---------------------------------------------------------------------------
// K1: layer-1 node transform. One block (256 thr) per node.
// thread t -> head t>>6, channel t&63. h1[n,t] = sum_k x[n,k]*W1[k,t].
// al_s1/al_d1 via wave reduction (wave == one head's 64 channels).
// ---------------------------------------------------------------------------
__global__ __launch_bounds__(256) void k1_node1(
    const float* __restrict__ x, const float* __restrict__ W1,
    const float* __restrict__ a_src1, const float* __restrict__ a_dst1,
    float* __restrict__ h1, float* __restrict__ al_s1, float* __restrict__ al_d1,
    int N) {
    int n = blockIdx.x;
    if (n >= N) return;
    int t = threadIdx.x;
    float h = 0.f;
#pragma unroll
    for (int k = 0; k < 5; ++k) h = fmaf(x[n * 5 + k], W1[k * 256 + t], h);
    h1[(size_t)n * 256 + t] = h;
    float s = wave_sum64(h * a_src1[t]);   // a_src1 flat [4*64] == t
    float d = wave_sum64(h * a_dst1[t]);
    if ((t & 63) == 0) {
        int head = t >> 6;
        al_s1[n * 4 + head] = s;
        al_d1[n * 4 + head] = d;
    }
}

// ---------------------------------------------------------------------------
// K2: layer-1 edge aggregation (atomics). One wave per edge; 4 edges/block.
// Unnormalized: agg1[dst,h,c] += exp(leaky(al_s[src,h]+al_d[dst,h])) * h1[src,h,c]
//               denom1[dst,h] += exp(...)
// (softmax max-shift elided: logits are O(1) by glorot arithmetic, exp is safe;
//  normalization happens in K3 — mathematically identical to the reference)
// ---------------------------------------------------------------------------
__global__ __launch_bounds__(256) void k2_edge1(
    const int* __restrict__ ei, int E, int Etot,
    const float* __restrict__ h1,
    const float* __restrict__ al_s1, const float* __restrict__ al_d1,
    float* __restrict__ agg1, float* __restrict__ denom1) {
    int wave = threadIdx.x >> 6;
    int lane = threadIdx.x & 63;
    int e = blockIdx.x * 4 + wave;
    if (e >= Etot) return;
    int src, dst;
    if (e < E) { src = ei[e]; dst = ei[E + e]; }
    else       { src = dst = e - E; }

    const float4 as = *reinterpret_cast<const float4*>(&al_s1[src * 4]);
    const float4 ad = *reinterpret_cast<const float4*>(&al_d1[dst * 4]);
    float v0 = as.x + ad.x, v1 = as.y + ad.y, v2 = as.z + ad.z, v3 = as.w + ad.w;
    v0 = v0 > 0.f ? v0 : NEG_SLOPE * v0;
    v1 = v1 > 0.f ? v1 : NEG_SLOPE * v1;
    v2 = v2 > 0.f ? v2 : NEG_SLOPE * v2;
    v3 = v3 > 0.f ? v3 : NEG_SLOPE * v3;
    float ex0 = __expf(v0), ex1 = __expf(v1), ex2 = __expf(v2), ex3 = __expf(v3);

    if (lane == 0) {  // static indexing (no runtime-indexed reg array)
        atomicAdd(&denom1[dst * 4 + 0], ex0);
        atomicAdd(&denom1[dst * 4 + 1], ex1);
        atomicAdd(&denom1[dst * 4 + 2], ex2);
        atomicAdd(&denom1[dst * 4 + 3], ex3);
    }
    const float* hs = &h1[(size_t)src * 256];
    float* ag = &agg1[(size_t)dst * 256];
    atomicAdd(&ag[0 * 64 + lane], ex0 * hs[0 * 64 + lane]);
    atomicAdd(&ag[1 * 64 + lane], ex1 * hs[1 * 64 + lane]);
    atomicAdd(&ag[2 * 64 + lane], ex2 * hs[2 * 64 + lane]);
    atomicAdd(&ag[3 * 64 + lane], ex3 * hs[3 * 64 + lane]);
}

// ---------------------------------------------------------------------------
// K3: layer-2 node transform. Block = 256 thr = 4 waves; 4 nodes/block.
// x2 = relu(agg1/denom1 + b1) (per node, into LDS); h2 = x2 @ W2 (W2 in LDS);
// al_s2/al_d2 via wave reduction.
// ---------------------------------------------------------------------------
__global__ __launch_bounds__(256) void k3_node2(
    const float* __restrict__ agg1, const float* __restrict__ denom1,
    const float* __restrict__ b1, const float* __restrict__ W2,
    const float* __restrict__ a_src2, const float* __restrict__ a_dst2,
    float* __restrict__ h2, float* __restrict__ al_s2, float* __restrict__ al_d2,
    int N) {
    __shared__ float W2s[256 * 64];   // 64 KiB, [j][c]
    __shared__ float x2s[4][256];
    int t = threadIdx.x;
    for (int i = t; i < 256 * 64; i += 256) W2s[i] = W2[i];
    __syncthreads();
    int wave = t >> 6, lane = t & 63;
    int n = blockIdx.x * 4 + wave;
    if (n >= N) return;

    const float4 dn = *reinterpret_cast<const float4*>(&denom1[n * 4]);
    float rd0 = 1.f / dn.x, rd1 = 1.f / dn.y, rd2 = 1.f / dn.z, rd3 = 1.f / dn.w;
    const float* ag = &agg1[(size_t)n * 256];
    {
        float v;
        v = fmaf(ag[0 * 64 + lane], rd0, b1[0 * 64 + lane]); x2s[wave][0 * 64 + lane] = v > 0.f ? v : 0.f;
        v = fmaf(ag[1 * 64 + lane], rd1, b1[1 * 64 + lane]); x2s[wave][1 * 64 + lane] = v > 0.f ? v : 0.f;
        v = fmaf(ag[2 * 64 + lane], rd2, b1[2 * 64 + lane]); x2s[wave][2 * 64 + lane] = v > 0.f ? v : 0.f;
        v = fmaf(ag[3 * 64 + lane], rd3, b1[3 * 64 + lane]); x2s[wave][3 * 64 + lane] = v > 0.f ? v : 0.f;
    }
    // same-wave LDS write->read: LDS ops execute in issue order per wave, no barrier needed
    float acc = 0.f;
#pragma unroll 8
    for (int j = 0; j < 256; ++j)
        acc = fmaf(x2s[wave][j], W2s[j * 64 + lane], acc);
    h2[(size_t)n * 64 + lane] = acc;
    float s = wave_sum64(acc * a_src2[lane]);
    float d = wave_sum64(acc * a_dst2[lane]);
    if (lane == 0) { al_s2[n] = s; al_d2[n] = d; }
}

// ---------------------------------------------------------------------------
// K4: layer-2 edge aggregation (atomics). One wave per edge; 4 edges/block.
// ---------------------------------------------------------------------------
__global__ __launch_bounds__(256) void k4_edge2(
    const int* __restrict__ ei, int E, int Etot,
    const float* __restrict__ h2,
    const float* __restrict__ al_s2, const float* __restrict__ al_d2,
    float* __restrict__ agg2, float* __restrict__ denom2) {
    int wave = threadIdx.x >> 6;
    int lane = threadIdx.x & 63;
    int e = blockIdx.x * 4 + wave;
    if (e >= Etot) return;
    int src, dst;
    if (e < E) { src = ei[e]; dst = ei[E + e]; }
    else       { src = dst = e - E; }
    float v = al_s2[src] + al_d2[dst];
    v = v > 0.f ? v : NEG_SLOPE * v;
    float ex = __expf(v);
    atomicAdd(&agg2[(size_t)dst * 64 + lane], ex * h2[(size_t)src * 64 + lane]);
    if (lane == 0) atomicAdd(&denom2[dst], ex);
}

// ---------------------------------------------------------------------------
// K5: final normalize + node-mean + bias. Block = 1 wave (64 thr), grid-stride.
// ---------------------------------------------------------------------------
__global__ __launch_bounds__(64) void k5_final(
    const float* __restrict__ agg2, const float* __restrict__ denom2,
    const float* __restrict__ b2, float* __restrict__ out, int N) {
    int lane = threadIdx.x;
    float acc = 0.f;
    for (int n = blockIdx.x; n < N; n += gridDim.x)
        acc += agg2[(size_t)n * 64 + lane] / denom2[n];
    float v = acc * (1.f / (float)N);
    if (blockIdx.x == 0) v += b2[lane];
    atomicAdd(&out[lane], v);
}

extern "C" void kernel_launch(void* const* d_in, const int* in_sizes, int n_in,
                              void* d_out, int out_size, void* d_ws, size_t ws_size,
                              hipStream_t stream) {
    const float* x     = (const float*)d_in[0];
    const int*   ei    = (const int*)d_in[1];
    const float* W1    = (const float*)d_in[2];
    const float* as1   = (const float*)d_in[3];
    const float* ad1   = (const float*)d_in[4];
    const float* b1    = (const float*)d_in[5];
    const float* W2    = (const float*)d_in[6];
    const float* as2   = (const float*)d_in[7];
    const float* ad2   = (const float*)d_in[8];
    const float* b2    = (const float*)d_in[9];
    float* out = (float*)d_out;

    const int F_in = in_sizes[2] / 256;        // W1: [F_in, 4*64]
    const int N = in_sizes[0] / F_in;
    const int E = in_sizes[1] / 2;
    const int Etot = E + N;

    float* ws = (float*)d_ws;
    float* h1     = ws;                         // N*256
    float* agg1   = h1 + (size_t)N * 256;       // N*256
    float* al_s1  = agg1 + (size_t)N * 256;     // N*4
    float* al_d1  = al_s1 + (size_t)N * 4;      // N*4
    float* denom1 = al_d1 + (size_t)N * 4;      // N*4
    float* h2     = denom1 + (size_t)N * 4;     // N*64
    float* al_s2  = h2 + (size_t)N * 64;        // N
    float* al_d2  = al_s2 + N;                  // N
    float* denom2 = al_d2 + N;                  // N
    float* agg2   = denom2 + N;                 // N*64

    hipMemsetAsync(agg1,   0, (size_t)N * 256 * sizeof(float), stream);
    hipMemsetAsync(denom1, 0, (size_t)N * 4 * sizeof(float), stream);
    hipMemsetAsync(agg2,   0, (size_t)N * 64 * sizeof(float), stream);
    hipMemsetAsync(denom2, 0, (size_t)N * sizeof(float), stream);
    hipMemsetAsync(out,    0, 64 * sizeof(float), stream);

    k1_node1<<<N, 256, 0, stream>>>(x, W1, as1, ad1, h1, al_s1, al_d1, N);
    k2_edge1<<<(Etot + 3) / 4, 256, 0, stream>>>(ei, E, Etot, h1, al_s1, al_d1, agg1, denom1);
    k3_node2<<<(N + 3) / 4, 256, 0, stream>>>(agg1, denom1, b1, W2, as2, ad2, h2, al_s2, al_d2, N);
    k4_edge2<<<(Etot + 3) / 4, 256, 0, stream>>>(ei, E, Etot, h2, al_s2, al_d2, agg2, denom2);
    k5_final<<<256, 64, 0, stream>>>(agg2, denom2, b2, out, N);
}

// Round 5
// 733.783 us; speedup vs baseline: 1.8689x; 1.8689x over previous
//
#include <hip/hip_runtime.h>

#define NEG_SLOPE 0.2f

__device__ __forceinline__ float wave_sum64(float v) {
#pragma unroll
    for (int off = 32; off >= 1; off >>= 1) v += __shfl_xor(v, off, 64);
    return v;
}

// ---------------------------------------------------------------------------
// CSR build: KB1 degree histogram -> KB2 single-block scan -> KB3 scatter.
// CSR is shared by both layers (same edge list). Only deg needs zeroing.
// ---------------------------------------------------------------------------
__global__ __launch_bounds__(256) void kb1_deg(
    const int* __restrict__ ei, int E, int Etot, int* __restrict__ deg) {
    int e = blockIdx.x * 256 + threadIdx.x;
    if (e >= Etot) return;
    int dst = (e < E) ? ei[E + e] : e - E;   // self-loops appended
    atomicAdd(&deg[dst], 1);
}

__global__ __launch_bounds__(1024) void kb2_scan(
    const int* __restrict__ deg, int N, int Etot,
    int* __restrict__ row_ptr, int* __restrict__ row_cur) {
    __shared__ int ps[1024];
    int t = threadIdx.x;
    int chunk = (N + 1023) >> 10;
    int i0 = t * chunk, i1 = min(N, i0 + chunk);
    int s = 0;
    for (int i = i0; i < i1; ++i) s += deg[i];
    ps[t] = s;
    __syncthreads();
    for (int off = 1; off < 1024; off <<= 1) {   // Hillis-Steele inclusive scan
        int v = (t >= off) ? ps[t - off] : 0;
        __syncthreads();
        ps[t] += v;
        __syncthreads();
    }
    int run = (t == 0) ? 0 : ps[t - 1];          // exclusive offset for my chunk
    for (int i = i0; i < i1; ++i) {
        row_ptr[i] = run; row_cur[i] = run;
        run += deg[i];
    }
    if (t == 1023) row_ptr[N] = Etot;
}

__global__ __launch_bounds__(256) void kb3_scatter(
    const int* __restrict__ ei, int E, int Etot,
    int* __restrict__ row_cur, int* __restrict__ csr_src) {
    int e = blockIdx.x * 256 + threadIdx.x;
    if (e >= Etot) return;
    int src, dst;
    if (e < E) { src = ei[e]; dst = ei[E + e]; }
    else       { src = dst = e - E; }
    int pos = atomicAdd(&row_cur[dst], 1);
    csr_src[pos] = src;
}

// ---------------------------------------------------------------------------
// K1: layer-1 node transform. One block (256 thr) per node.
// thread t -> head t>>6, channel t&63. al via wave reduction (wave == head).
// ---------------------------------------------------------------------------
__global__ __launch_bounds__(256) void k1_node1(
    const float* __restrict__ x, const float* __restrict__ W1,
    const float* __restrict__ a_src1, const float* __restrict__ a_dst1,
    float* __restrict__ h1, float* __restrict__ al_s1, float* __restrict__ al_d1,
    int N) {
    int n = blockIdx.x;
    if (n >= N) return;
    int t = threadIdx.x;
    float h = 0.f;
#pragma unroll
    for (int k = 0; k < 5; ++k) h = fmaf(x[n * 5 + k], W1[k * 256 + t], h);
    h1[(size_t)n * 256 + t] = h;
    float s = wave_sum64(h * a_src1[t]);
    float d = wave_sum64(h * a_dst1[t]);
    if ((t & 63) == 0) {
        int head = t >> 6;
        al_s1[n * 4 + head] = s;
        al_d1[n * 4 + head] = d;
    }
}

// ---------------------------------------------------------------------------
// K2': layer-1 aggregation, gather-style (no atomics). One wave per dst node;
// lane = channel-within-head, 4 heads looped. Edge srcs loaded 64-at-a-time
// (coalesced) then broadcast via shfl. Accumulate in registers; epilogue
// fuses softmax-normalize + b1 + relu -> writes x2 (layer-2 input) directly.
// Softmax max-shift elided (exact by shift-invariance; logits are O(1)).
// ---------------------------------------------------------------------------
__global__ __launch_bounds__(256) void k2_gather1(
    const int* __restrict__ csr_src, const int* __restrict__ row_ptr,
    const float* __restrict__ h1, const float* __restrict__ al_s1,
    const float* __restrict__ al_d1, const float* __restrict__ b1,
    float* __restrict__ x2, int N) {
    int wave = threadIdx.x >> 6, lane = threadIdx.x & 63;
    int n = blockIdx.x * 4 + wave;
    if (n >= N) return;
    int beg = row_ptr[n], end = row_ptr[n + 1];
    const float4 ad = *reinterpret_cast<const float4*>(&al_d1[n * 4]);
    float a0 = 0.f, a1 = 0.f, a2 = 0.f, a3 = 0.f;
    float d0 = 0.f, d1 = 0.f, d2 = 0.f, d3 = 0.f;
    for (int base = beg; base < end; base += 64) {
        int nn = min(64, end - base);
        int srcv = (base + lane < end) ? csr_src[base + lane] : 0;
        for (int i = 0; i < nn; ++i) {
            int src = __shfl(srcv, i, 64);
            const float4 as = *reinterpret_cast<const float4*>(&al_s1[src * 4]);
            float v0 = as.x + ad.x, v1 = as.y + ad.y, v2 = as.z + ad.z, v3 = as.w + ad.w;
            v0 = v0 > 0.f ? v0 : NEG_SLOPE * v0;
            v1 = v1 > 0.f ? v1 : NEG_SLOPE * v1;
            v2 = v2 > 0.f ? v2 : NEG_SLOPE * v2;
            v3 = v3 > 0.f ? v3 : NEG_SLOPE * v3;
            float ex0 = __expf(v0), ex1 = __expf(v1), ex2 = __expf(v2), ex3 = __expf(v3);
            const float* hs = &h1[(size_t)src * 256];
            a0 = fmaf(ex0, hs[0 * 64 + lane], a0); d0 += ex0;
            a1 = fmaf(ex1, hs[1 * 64 + lane], a1); d1 += ex1;
            a2 = fmaf(ex2, hs[2 * 64 + lane], a2); d2 += ex2;
            a3 = fmaf(ex3, hs[3 * 64 + lane], a3); d3 += ex3;
        }
    }
    float* xo = &x2[(size_t)n * 256];
    float r;
    r = a0 / d0 + b1[0 * 64 + lane]; xo[0 * 64 + lane] = r > 0.f ? r : 0.f;
    r = a1 / d1 + b1[1 * 64 + lane]; xo[1 * 64 + lane] = r > 0.f ? r : 0.f;
    r = a2 / d2 + b1[2 * 64 + lane]; xo[2 * 64 + lane] = r > 0.f ? r : 0.f;
    r = a3 / d3 + b1[3 * 64 + lane]; xo[3 * 64 + lane] = r > 0.f ? r : 0.f;
}

// ---------------------------------------------------------------------------
// K3': layer-2 node transform. Block = 4 waves = 4 nodes; W2 [256,64] in LDS.
// x-row held in 4 regs/lane, broadcast via shfl (halves LDS read pressure).
// ---------------------------------------------------------------------------
__global__ __launch_bounds__(256) void k3_node2(
    const float* __restrict__ x2, const float* __restrict__ W2,
    const float* __restrict__ a_src2, const float* __restrict__ a_dst2,
    float* __restrict__ h2, float* __restrict__ al_s2, float* __restrict__ al_d2,
    int N) {
    __shared__ float W2s[256 * 64];   // 64 KiB, [j][c]
    int t = threadIdx.x;
    for (int i = t; i < 256 * 64; i += 256) W2s[i] = W2[i];
    __syncthreads();
    int wave = t >> 6, lane = t & 63;
    int n = blockIdx.x * 4 + wave;
    if (n >= N) return;
    const float* xr = &x2[(size_t)n * 256];
    float xv0 = xr[0 * 64 + lane], xv1 = xr[1 * 64 + lane];
    float xv2 = xr[2 * 64 + lane], xv3 = xr[3 * 64 + lane];
    float acc = 0.f;
#pragma unroll 8
    for (int j = 0; j < 64; ++j) acc = fmaf(__shfl(xv0, j, 64), W2s[(0 * 64 + j) * 64 + lane], acc);
#pragma unroll 8
    for (int j = 0; j < 64; ++j) acc = fmaf(__shfl(xv1, j, 64), W2s[(1 * 64 + j) * 64 + lane], acc);
#pragma unroll 8
    for (int j = 0; j < 64; ++j) acc = fmaf(__shfl(xv2, j, 64), W2s[(2 * 64 + j) * 64 + lane], acc);
#pragma unroll 8
    for (int j = 0; j < 64; ++j) acc = fmaf(__shfl(xv3, j, 64), W2s[(3 * 64 + j) * 64 + lane], acc);
    h2[(size_t)n * 64 + lane] = acc;
    float s = wave_sum64(acc * a_src2[lane]);
    float d = wave_sum64(acc * a_dst2[lane]);
    if (lane == 0) { al_s2[n] = s; al_d2[n] = d; }
}

// ---------------------------------------------------------------------------
// K4': layer-2 aggregation, gather-style. One wave per dst; lane = channel.
// al_s2 prefetched lane-parallel alongside srcs, both shfl-broadcast.
// Writes normalized o2 directly (no atomics, no denom buffer).
// ---------------------------------------------------------------------------
__global__ __launch_bounds__(256) void k4_gather2(
    const int* __restrict__ csr_src, const int* __restrict__ row_ptr,
    const float* __restrict__ h2, const float* __restrict__ al_s2,
    const float* __restrict__ al_d2, float* __restrict__ o2, int N) {
    int wave = threadIdx.x >> 6, lane = threadIdx.x & 63;
    int n = blockIdx.x * 4 + wave;
    if (n >= N) return;
    int beg = row_ptr[n], end = row_ptr[n + 1];
    float ad = al_d2[n];
    float a = 0.f, d = 0.f;
    for (int base = beg; base < end; base += 64) {
        int nn = min(64, end - base);
        bool ok = (base + lane < end);
        int srcv = ok ? csr_src[base + lane] : 0;
        float asv = ok ? al_s2[srcv] : 0.f;
        for (int i = 0; i < nn; ++i) {
            int src = __shfl(srcv, i, 64);
            float as = __shfl(asv, i, 64);
            float v = as + ad;
            v = v > 0.f ? v : NEG_SLOPE * v;
            float ex = __expf(v);
            a = fmaf(ex, h2[(size_t)src * 64 + lane], a);
            d += ex;
        }
    }
    o2[(size_t)n * 64 + lane] = a / d;
}

// ---------------------------------------------------------------------------
// K5: node-mean + bias. Block = 1 wave, grid-stride over nodes.
// ---------------------------------------------------------------------------
__global__ __launch_bounds__(64) void k5_final(
    const float* __restrict__ o2, const float* __restrict__ b2,
    float* __restrict__ out, int N) {
    int lane = threadIdx.x;
    float acc = 0.f;
    for (int n = blockIdx.x; n < N; n += gridDim.x)
        acc += o2[(size_t)n * 64 + lane];
    float v = acc * (1.f / (float)N);
    if (blockIdx.x == 0) v += b2[lane];
    atomicAdd(&out[lane], v);
}

extern "C" void kernel_launch(void* const* d_in, const int* in_sizes, int n_in,
                              void* d_out, int out_size, void* d_ws, size_t ws_size,
                              hipStream_t stream) {
    const float* x   = (const float*)d_in[0];
    const int*   ei  = (const int*)d_in[1];
    const float* W1  = (const float*)d_in[2];
    const float* as1 = (const float*)d_in[3];
    const float* ad1 = (const float*)d_in[4];
    const float* b1  = (const float*)d_in[5];
    const float* W2  = (const float*)d_in[6];
    const float* as2 = (const float*)d_in[7];
    const float* ad2 = (const float*)d_in[8];
    const float* b2  = (const float*)d_in[9];
    float* out = (float*)d_out;

    const int F_in = in_sizes[2] / 256;        // W1: [F_in, 4*64]
    const int N = in_sizes[0] / F_in;
    const int E = in_sizes[1] / 2;
    const int Etot = E + N;

    // Workspace layout (aliasing: al_s2/al_d2 reuse al_s1/al_d1 [dead after K2'];
    // o2 reuses x2's space [dead after K3']). ~121 MB total.
    float* ws    = (float*)d_ws;
    float* h1    = ws;                          // N*256
    float* x2    = h1 + (size_t)N * 256;        // N*256
    float* h2    = x2 + (size_t)N * 256;        // N*64
    float* al_s1 = h2 + (size_t)N * 64;         // N*4
    float* al_d1 = al_s1 + (size_t)N * 4;       // N*4
    int* deg     = (int*)(al_d1 + (size_t)N * 4);  // N
    int* row_cur = deg + N;                     // N
    int* row_ptr = row_cur + N;                 // N+1
    int* csr_src = row_ptr + N + 1;             // Etot
    float* o2    = x2;                          // alias
    float* al_s2 = al_s1;                       // alias
    float* al_d2 = al_d1;                       // alias

    hipMemsetAsync(deg, 0, (size_t)N * sizeof(int), stream);
    hipMemsetAsync(out, 0, 64 * sizeof(float), stream);

    kb1_deg    <<<(Etot + 255) / 256, 256, 0, stream>>>(ei, E, Etot, deg);
    kb2_scan   <<<1, 1024, 0, stream>>>(deg, N, Etot, row_ptr, row_cur);
    kb3_scatter<<<(Etot + 255) / 256, 256, 0, stream>>>(ei, E, Etot, row_cur, csr_src);

    k1_node1  <<<N, 256, 0, stream>>>(x, W1, as1, ad1, h1, al_s1, al_d1, N);
    k2_gather1<<<(N + 3) / 4, 256, 0, stream>>>(csr_src, row_ptr, h1, al_s1, al_d1, b1, x2, N);
    k3_node2  <<<(N + 3) / 4, 256, 0, stream>>>(x2, W2, as2, ad2, h2, al_s2, al_d2, N);
    k4_gather2<<<(N + 3) / 4, 256, 0, stream>>>(csr_src, row_ptr, h2, al_s2, al_d2, o2, N);
    k5_final  <<<256, 64, 0, stream>>>(o2, b2, out, N);
}

// Round 6
// 691.854 us; speedup vs baseline: 1.9821x; 1.0606x over previous
//
#include <hip/hip_runtime.h>
#include <hip/hip_bf16.h>

#define NEG_SLOPE 0.2f

__device__ __forceinline__ float wave_sum64(float v) {
#pragma unroll
    for (int off = 32; off >= 1; off >>= 1) v += __shfl_xor(v, off, 64);
    return v;
}

__device__ __forceinline__ float bf2f(unsigned short u) {
    return __uint_as_float((unsigned int)u << 16);
}

// ---------------------------------------------------------------------------
// CSR build: KB1 degree histogram -> KB2 single-block scan -> KB3 scatter.
// ---------------------------------------------------------------------------
__global__ __launch_bounds__(256) void kb1_deg(
    const int* __restrict__ ei, int E, int Etot, int* __restrict__ deg) {
    int e = blockIdx.x * 256 + threadIdx.x;
    if (e >= Etot) return;
    int dst = (e < E) ? ei[E + e] : e - E;   // self-loops appended
    atomicAdd(&deg[dst], 1);
}

__global__ __launch_bounds__(1024) void kb2_scan(
    const int* __restrict__ deg, int N, int Etot,
    int* __restrict__ row_ptr, int* __restrict__ row_cur) {
    __shared__ int ps[1024];
    int t = threadIdx.x;
    int chunk = (N + 1023) >> 10;
    int i0 = t * chunk, i1 = min(N, i0 + chunk);
    int s = 0;
    for (int i = i0; i < i1; ++i) s += deg[i];
    ps[t] = s;
    __syncthreads();
    for (int off = 1; off < 1024; off <<= 1) {   // Hillis-Steele inclusive scan
        int v = (t >= off) ? ps[t - off] : 0;
        __syncthreads();
        ps[t] += v;
        __syncthreads();
    }
    int run = (t == 0) ? 0 : ps[t - 1];
    for (int i = i0; i < i1; ++i) {
        row_ptr[i] = run; row_cur[i] = run;
        run += deg[i];
    }
    if (t == 1023) row_ptr[N] = Etot;
}

__global__ __launch_bounds__(256) void kb3_scatter(
    const int* __restrict__ ei, int E, int Etot,
    int* __restrict__ row_cur, int* __restrict__ csr_src) {
    int e = blockIdx.x * 256 + threadIdx.x;
    if (e >= Etot) return;
    int src, dst;
    if (e < E) { src = ei[e]; dst = ei[E + e]; }
    else       { src = dst = e - E; }
    int pos = atomicAdd(&row_cur[dst], 1);
    csr_src[pos] = src;
}

// ---------------------------------------------------------------------------
// K1: layer-1 node transform. One block (256 thr) per node.
// Computes h in fp32 (exact al_s/al_d), stores h1 as bf16 in head-interleaved
// layout h1b[n*256 + ch*4 + head] so K2's lane reads 4 head-values as 8B.
// ---------------------------------------------------------------------------
__global__ __launch_bounds__(256) void k1_node1(
    const float* __restrict__ x, const float* __restrict__ W1,
    const float* __restrict__ a_src1, const float* __restrict__ a_dst1,
    unsigned short* __restrict__ h1b, float* __restrict__ al_s1,
    float* __restrict__ al_d1, int N) {
    int n = blockIdx.x;
    if (n >= N) return;
    int t = threadIdx.x;
    float h = 0.f;
#pragma unroll
    for (int k = 0; k < 5; ++k) h = fmaf(x[n * 5 + k], W1[k * 256 + t], h);
    int head = t >> 6, ch = t & 63;
    __hip_bfloat16 hb = __float2bfloat16(h);   // RNE
    h1b[(size_t)n * 256 + ch * 4 + head] = *reinterpret_cast<unsigned short*>(&hb);
    float s = wave_sum64(h * a_src1[t]);
    float d = wave_sum64(h * a_dst1[t]);
    if (ch == 0) {
        al_s1[n * 4 + head] = s;
        al_d1[n * 4 + head] = d;
    }
}

// ---------------------------------------------------------------------------
// K2': layer-1 aggregation, gather-style. One wave per dst node; lane = ch.
// Per edge: one 8B load of 4 bf16 head-values + one 16B al_s1 load.
// Epilogue fuses softmax-normalize + b1 + relu -> writes x2 (fp32).
// Softmax max-shift elided (exact; logits O(1)).
// ---------------------------------------------------------------------------
__global__ __launch_bounds__(256) void k2_gather1(
    const int* __restrict__ csr_src, const int* __restrict__ row_ptr,
    const unsigned short* __restrict__ h1b, const float* __restrict__ al_s1,
    const float* __restrict__ al_d1, const float* __restrict__ b1,
    float* __restrict__ x2, int N) {
    int wave = threadIdx.x >> 6, lane = threadIdx.x & 63;
    int n = blockIdx.x * 4 + wave;
    if (n >= N) return;
    int beg = row_ptr[n], end = row_ptr[n + 1];
    const float4 ad = *reinterpret_cast<const float4*>(&al_d1[n * 4]);
    float a0 = 0.f, a1 = 0.f, a2 = 0.f, a3 = 0.f;
    float d0 = 0.f, d1 = 0.f, d2 = 0.f, d3 = 0.f;
    for (int base = beg; base < end; base += 64) {
        int nn = min(64, end - base);
        int srcv = (base + lane < end) ? csr_src[base + lane] : 0;
        for (int i = 0; i < nn; ++i) {
            int src = __shfl(srcv, i, 64);
            const float4 as = *reinterpret_cast<const float4*>(&al_s1[src * 4]);
            float v0 = as.x + ad.x, v1 = as.y + ad.y, v2 = as.z + ad.z, v3 = as.w + ad.w;
            v0 = v0 > 0.f ? v0 : NEG_SLOPE * v0;
            v1 = v1 > 0.f ? v1 : NEG_SLOPE * v1;
            v2 = v2 > 0.f ? v2 : NEG_SLOPE * v2;
            v3 = v3 > 0.f ? v3 : NEG_SLOPE * v3;
            float ex0 = __expf(v0), ex1 = __expf(v1), ex2 = __expf(v2), ex3 = __expf(v3);
            const ushort4 u = *reinterpret_cast<const ushort4*>(
                &h1b[(size_t)src * 256 + lane * 4]);
            a0 = fmaf(ex0, bf2f(u.x), a0); d0 += ex0;
            a1 = fmaf(ex1, bf2f(u.y), a1); d1 += ex1;
            a2 = fmaf(ex2, bf2f(u.z), a2); d2 += ex2;
            a3 = fmaf(ex3, bf2f(u.w), a3); d3 += ex3;
        }
    }
    float* xo = &x2[(size_t)n * 256];
    float r;
    r = a0 / d0 + b1[0 * 64 + lane]; xo[0 * 64 + lane] = r > 0.f ? r : 0.f;
    r = a1 / d1 + b1[1 * 64 + lane]; xo[1 * 64 + lane] = r > 0.f ? r : 0.f;
    r = a2 / d2 + b1[2 * 64 + lane]; xo[2 * 64 + lane] = r > 0.f ? r : 0.f;
    r = a3 / d3 + b1[3 * 64 + lane]; xo[3 * 64 + lane] = r > 0.f ? r : 0.f;
}

// ---------------------------------------------------------------------------
// K3'': layer-2 GEMM, W2-stationary-in-registers. One wave per block;
// lane = output col; w[256] = W2 column (fully unrolled -> VGPRs).
// Row index blockIdx-derived => wave-uniform => x-row loads become s_load;
// inner loop = pure v_fmac(SGPR x, VGPR w) with 4 acc chains. No LDS.
// ---------------------------------------------------------------------------
__global__ __launch_bounds__(64) void k3_node2(
    const float* __restrict__ x2, const float* __restrict__ W2,
    const float* __restrict__ a_src2, const float* __restrict__ a_dst2,
    float* __restrict__ h2, float* __restrict__ al_s2, float* __restrict__ al_d2,
    int N, int nblocks) {
    int lane = threadIdx.x;
    float w[256];
#pragma unroll
    for (int k = 0; k < 256; ++k) w[k] = W2[k * 64 + lane];
    float va = a_src2[lane], vb = a_dst2[lane];
    for (int n = blockIdx.x; n < N; n += nblocks) {
        const float* __restrict__ xr = x2 + (size_t)n * 256;
        float acc0 = 0.f, acc1 = 0.f, acc2 = 0.f, acc3 = 0.f;
#pragma unroll
        for (int k = 0; k < 256; k += 4) {
            acc0 = fmaf(xr[k + 0], w[k + 0], acc0);
            acc1 = fmaf(xr[k + 1], w[k + 1], acc1);
            acc2 = fmaf(xr[k + 2], w[k + 2], acc2);
            acc3 = fmaf(xr[k + 3], w[k + 3], acc3);
        }
        float acc = (acc0 + acc1) + (acc2 + acc3);
        h2[(size_t)n * 64 + lane] = acc;
        float s = wave_sum64(acc * va);
        float d = wave_sum64(acc * vb);
        if (lane == 0) { al_s2[n] = s; al_d2[n] = d; }
    }
}

// ---------------------------------------------------------------------------
// K4': layer-2 aggregation, gather-style. One wave per dst; lane = channel.
// ---------------------------------------------------------------------------
__global__ __launch_bounds__(256) void k4_gather2(
    const int* __restrict__ csr_src, const int* __restrict__ row_ptr,
    const float* __restrict__ h2, const float* __restrict__ al_s2,
    const float* __restrict__ al_d2, float* __restrict__ o2, int N) {
    int wave = threadIdx.x >> 6, lane = threadIdx.x & 63;
    int n = blockIdx.x * 4 + wave;
    if (n >= N) return;
    int beg = row_ptr[n], end = row_ptr[n + 1];
    float ad = al_d2[n];
    float a = 0.f, d = 0.f;
    for (int base = beg; base < end; base += 64) {
        int nn = min(64, end - base);
        bool ok = (base + lane < end);
        int srcv = ok ? csr_src[base + lane] : 0;
        float asv = ok ? al_s2[srcv] : 0.f;
        for (int i = 0; i < nn; ++i) {
            int src = __shfl(srcv, i, 64);
            float as = __shfl(asv, i, 64);
            float v = as + ad;
            v = v > 0.f ? v : NEG_SLOPE * v;
            float ex = __expf(v);
            a = fmaf(ex, h2[(size_t)src * 64 + lane], a);
            d += ex;
        }
    }
    o2[(size_t)n * 64 + lane] = a / d;
}

// ---------------------------------------------------------------------------
// K5: node-mean + bias. Block = 1 wave, grid-stride over nodes.
// ---------------------------------------------------------------------------
__global__ __launch_bounds__(64) void k5_final(
    const float* __restrict__ o2, const float* __restrict__ b2,
    float* __restrict__ out, int N) {
    int lane = threadIdx.x;
    float acc = 0.f;
    for (int n = blockIdx.x; n < N; n += gridDim.x)
        acc += o2[(size_t)n * 64 + lane];
    float v = acc * (1.f / (float)N);
    if (blockIdx.x == 0) v += b2[lane];
    atomicAdd(&out[lane], v);
}

extern "C" void kernel_launch(void* const* d_in, const int* in_sizes, int n_in,
                              void* d_out, int out_size, void* d_ws, size_t ws_size,
                              hipStream_t stream) {
    const float* x   = (const float*)d_in[0];
    const int*   ei  = (const int*)d_in[1];
    const float* W1  = (const float*)d_in[2];
    const float* as1 = (const float*)d_in[3];
    const float* ad1 = (const float*)d_in[4];
    const float* b1  = (const float*)d_in[5];
    const float* W2  = (const float*)d_in[6];
    const float* as2 = (const float*)d_in[7];
    const float* ad2 = (const float*)d_in[8];
    const float* b2  = (const float*)d_in[9];
    float* out = (float*)d_out;

    const int F_in = in_sizes[2] / 256;        // W1: [F_in, 4*64]
    const int N = in_sizes[0] / F_in;
    const int E = in_sizes[1] / 2;
    const int Etot = E + N;

    // Workspace: h1b bf16 (N*256 ushort = N*128 "floats"), then fp32/int buffers.
    // Aliases: o2=x2 (x2 dead after K3), al_s2/al_d2 = al_s1/al_d1 (dead after K2).
    unsigned short* h1b = (unsigned short*)d_ws;   // N*256 ushort
    float* x2    = (float*)(h1b + (size_t)N * 256);   // N*256 f32 (16B-aligned: N*512B)
    float* h2    = x2 + (size_t)N * 256;           // N*64
    float* al_s1 = h2 + (size_t)N * 64;            // N*4
    float* al_d1 = al_s1 + (size_t)N * 4;          // N*4
    int* deg     = (int*)(al_d1 + (size_t)N * 4);  // N
    int* row_cur = deg + N;                        // N
    int* row_ptr = row_cur + N;                    // N+1
    int* csr_src = row_ptr + N + 1;                // Etot
    float* o2    = x2;                             // alias
    float* al_s2 = al_s1;                          // alias
    float* al_d2 = al_d1;                          // alias

    hipMemsetAsync(deg, 0, (size_t)N * sizeof(int), stream);
    hipMemsetAsync(out, 0, 64 * sizeof(float), stream);

    kb1_deg    <<<(Etot + 255) / 256, 256, 0, stream>>>(ei, E, Etot, deg);
    kb2_scan   <<<1, 1024, 0, stream>>>(deg, N, Etot, row_ptr, row_cur);
    kb3_scatter<<<(Etot + 255) / 256, 256, 0, stream>>>(ei, E, Etot, row_cur, csr_src);

    k1_node1  <<<N, 256, 0, stream>>>(x, W1, as1, ad1, h1b, al_s1, al_d1, N);
    k2_gather1<<<(N + 3) / 4, 256, 0, stream>>>(csr_src, row_ptr, h1b, al_s1, al_d1, b1, x2, N);
    const int K3_BLOCKS = 1024;   // 256 CU x 4 SIMD, 1 wave each (VGPR ~270)
    k3_node2  <<<K3_BLOCKS, 64, 0, stream>>>(x2, W2, as2, ad2, h2, al_s2, al_d2, N, K3_BLOCKS);
    k4_gather2<<<(N + 3) / 4, 256, 0, stream>>>(csr_src, row_ptr, h2, al_s2, al_d2, o2, N);
    k5_final  <<<256, 64, 0, stream>>>(o2, b2, out, N);
}

// Round 8
// 518.547 us; speedup vs baseline: 2.6446x; 1.3342x over previous
//
#include <hip/hip_runtime.h>
#include <hip/hip_bf16.h>

#define NEG_SLOPE 0.2f

typedef __attribute__((ext_vector_type(8))) short short8;   // 8 bf16 (4 VGPRs)
typedef __attribute__((ext_vector_type(4))) float f32x4;

__device__ __forceinline__ float wave_sum64(float v) {
#pragma unroll
    for (int off = 32; off >= 1; off >>= 1) v += __shfl_xor(v, off, 64);
    return v;
}

__device__ __forceinline__ float bf2f(unsigned short u) {
    return __uint_as_float((unsigned int)u << 16);
}

__device__ __forceinline__ unsigned short f2bf(float f) {
    __hip_bfloat16 hb = __float2bfloat16(f);   // RNE
    return *reinterpret_cast<unsigned short*>(&hb);
}

// ---------------------------------------------------------------------------
// CSR build: KB1 degree histogram -> KB2 single-block scan -> KB3 scatter.
// ---------------------------------------------------------------------------
__global__ __launch_bounds__(256) void kb1_deg(
    const int* __restrict__ ei, int E, int Etot, int* __restrict__ deg) {
    int e = blockIdx.x * 256 + threadIdx.x;
    if (e >= Etot) return;
    int dst = (e < E) ? ei[E + e] : e - E;   // self-loops appended
    atomicAdd(&deg[dst], 1);
}

__global__ __launch_bounds__(1024) void kb2_scan(
    const int* __restrict__ deg, int N, int Etot,
    int* __restrict__ row_ptr, int* __restrict__ row_cur) {
    __shared__ int ps[1024];
    int t = threadIdx.x;
    int chunk = (N + 1023) >> 10;
    int i0 = t * chunk, i1 = min(N, i0 + chunk);
    int s = 0;
    for (int i = i0; i < i1; ++i) s += deg[i];
    ps[t] = s;
    __syncthreads();
    for (int off = 1; off < 1024; off <<= 1) {   // Hillis-Steele inclusive scan
        int v = (t >= off) ? ps[t - off] : 0;
        __syncthreads();
        ps[t] += v;
        __syncthreads();
    }
    int run = (t == 0) ? 0 : ps[t - 1];
    for (int i = i0; i < i1; ++i) {
        row_ptr[i] = run; row_cur[i] = run;
        run += deg[i];
    }
    if (t == 1023) row_ptr[N] = Etot;
}

__global__ __launch_bounds__(256) void kb3_scatter(
    const int* __restrict__ ei, int E, int Etot,
    int* __restrict__ row_cur, int* __restrict__ csr_src) {
    int e = blockIdx.x * 256 + threadIdx.x;
    if (e >= Etot) return;
    int src, dst;
    if (e < E) { src = ei[e]; dst = ei[E + e]; }
    else       { src = dst = e - E; }
    int pos = atomicAdd(&row_cur[dst], 1);
    csr_src[pos] = src;
}

// ---------------------------------------------------------------------------
// KW: pack W2 [256,64] f32 -> W2t [64 cols][256 k] bf16 (B-fragment friendly:
// contiguous k per col). 16384 elements, one-shot.
// ---------------------------------------------------------------------------
__global__ __launch_bounds__(256) void kw_pack(
    const float* __restrict__ W2, unsigned short* __restrict__ W2t) {
    int i = blockIdx.x * 256 + threadIdx.x;   // grid 64 blocks
    if (i >= 64 * 256) return;
    int c = i >> 8, k = i & 255;
    W2t[c * 256 + k] = f2bf(W2[k * 64 + c]);
}

// ---------------------------------------------------------------------------
// K1: layer-1 node transform. One block (256 thr) per node.
// h in fp32 (exact al_s/al_d); h1 stored bf16 head-interleaved
// h1b[n*256 + ch*4 + head] so K2's lane reads 4 head-values as one 8B load.
// ---------------------------------------------------------------------------
__global__ __launch_bounds__(256) void k1_node1(
    const float* __restrict__ x, const float* __restrict__ W1,
    const float* __restrict__ a_src1, const float* __restrict__ a_dst1,
    unsigned short* __restrict__ h1b, float* __restrict__ al_s1,
    float* __restrict__ al_d1, int N) {
    int n = blockIdx.x;
    if (n >= N) return;
    int t = threadIdx.x;
    float h = 0.f;
#pragma unroll
    for (int k = 0; k < 5; ++k) h = fmaf(x[n * 5 + k], W1[k * 256 + t], h);
    int head = t >> 6, ch = t & 63;
    h1b[(size_t)n * 256 + ch * 4 + head] = f2bf(h);
    float s = wave_sum64(h * a_src1[t]);
    float d = wave_sum64(h * a_dst1[t]);
    if (ch == 0) {
        al_s1[n * 4 + head] = s;
        al_d1[n * 4 + head] = d;
    }
}

// ---------------------------------------------------------------------------
// K2': layer-1 aggregation, gather-style. One wave per dst node; lane = ch.
// Per edge: one 8B load of 4 bf16 head-values + one 16B al_s1 load.
// Epilogue fuses softmax-normalize + b1 + relu -> writes x2b (bf16, layer-2
// GEMM A-operand). Softmax max-shift elided (exact; logits O(1)).
// ---------------------------------------------------------------------------
__global__ __launch_bounds__(256) void k2_gather1(
    const int* __restrict__ csr_src, const int* __restrict__ row_ptr,
    const unsigned short* __restrict__ h1b, const float* __restrict__ al_s1,
    const float* __restrict__ al_d1, const float* __restrict__ b1,
    unsigned short* __restrict__ x2b, int N) {
    int wave = threadIdx.x >> 6, lane = threadIdx.x & 63;
    int n = blockIdx.x * 4 + wave;
    if (n >= N) return;
    int beg = row_ptr[n], end = row_ptr[n + 1];
    const float4 ad = *reinterpret_cast<const float4*>(&al_d1[n * 4]);
    float a0 = 0.f, a1 = 0.f, a2 = 0.f, a3 = 0.f;
    float d0 = 0.f, d1 = 0.f, d2 = 0.f, d3 = 0.f;
    for (int base = beg; base < end; base += 64) {
        int nn = min(64, end - base);
        int srcv = (base + lane < end) ? csr_src[base + lane] : 0;
        for (int i = 0; i < nn; ++i) {
            int src = __shfl(srcv, i, 64);
            const float4 as = *reinterpret_cast<const float4*>(&al_s1[src * 4]);
            float v0 = as.x + ad.x, v1 = as.y + ad.y, v2 = as.z + ad.z, v3 = as.w + ad.w;
            v0 = v0 > 0.f ? v0 : NEG_SLOPE * v0;
            v1 = v1 > 0.f ? v1 : NEG_SLOPE * v1;
            v2 = v2 > 0.f ? v2 : NEG_SLOPE * v2;
            v3 = v3 > 0.f ? v3 : NEG_SLOPE * v3;
            float ex0 = __expf(v0), ex1 = __expf(v1), ex2 = __expf(v2), ex3 = __expf(v3);
            const ushort4 u = *reinterpret_cast<const ushort4*>(
                &h1b[(size_t)src * 256 + lane * 4]);
            a0 = fmaf(ex0, bf2f(u.x), a0); d0 += ex0;
            a1 = fmaf(ex1, bf2f(u.y), a1); d1 += ex1;
            a2 = fmaf(ex2, bf2f(u.z), a2); d2 += ex2;
            a3 = fmaf(ex3, bf2f(u.w), a3); d3 += ex3;
        }
    }
    unsigned short* xo = &x2b[(size_t)n * 256];
    float r;
    r = a0 / d0 + b1[0 * 64 + lane]; xo[0 * 64 + lane] = f2bf(r > 0.f ? r : 0.f);
    r = a1 / d1 + b1[1 * 64 + lane]; xo[1 * 64 + lane] = f2bf(r > 0.f ? r : 0.f);
    r = a2 / d2 + b1[2 * 64 + lane]; xo[2 * 64 + lane] = f2bf(r > 0.f ? r : 0.f);
    r = a3 / d3 + b1[3 * 64 + lane]; xo[3 * 64 + lane] = f2bf(r > 0.f ? r : 0.f);
}

// ---------------------------------------------------------------------------
// K3 (MFMA): h2 = x2b @ W2, [N,256]@[256,64] bf16->f32.
// Block = 4 waves = 64 rows; wave = 16-row M-tile, 4 N-tiles of 16 cols,
// K=256 in 8 steps of 32 via mfma_f32_16x16x32_bf16.
// A frag: lane l -> row l&15, k=(l>>4)*8+j (row-major x2b, one 16B load).
// B frag: lane l -> col l&15, same k (col-major W2t, one 16B load).
// D: col=lane&15, row=(lane>>4)*4+reg [m89].
// al_s2/al_d2 fused: per-lane partials + 16-lane shfl_xor reduce.
// Assumes N % 16 == 0 (N=50000).
// ---------------------------------------------------------------------------
__global__ __launch_bounds__(256) void k3_mfma(
    const unsigned short* __restrict__ x2b, const unsigned short* __restrict__ W2t,
    const float* __restrict__ a_src2, const float* __restrict__ a_dst2,
    float* __restrict__ h2, float* __restrict__ al_s2, float* __restrict__ al_d2,
    int N) {
    int w = threadIdx.x >> 6, l = threadIdx.x & 63;
    int m0 = blockIdx.x * 64 + w * 16;
    if (m0 >= N) return;
    int lr = l & 15, lg = l >> 4;

    short8 b0[8], b1f[8], b2f[8], b3f[8];   // full W2 in regs (128 VGPR)
#pragma unroll
    for (int kk = 0; kk < 8; ++kk) {
        b0[kk]  = *reinterpret_cast<const short8*>(&W2t[(0 * 16 + lr) * 256 + kk * 32 + lg * 8]);
        b1f[kk] = *reinterpret_cast<const short8*>(&W2t[(1 * 16 + lr) * 256 + kk * 32 + lg * 8]);
        b2f[kk] = *reinterpret_cast<const short8*>(&W2t[(2 * 16 + lr) * 256 + kk * 32 + lg * 8]);
        b3f[kk] = *reinterpret_cast<const short8*>(&W2t[(3 * 16 + lr) * 256 + kk * 32 + lg * 8]);
    }
    short8 a[8];
#pragma unroll
    for (int kk = 0; kk < 8; ++kk)
        a[kk] = *reinterpret_cast<const short8*>(&x2b[(size_t)(m0 + lr) * 256 + kk * 32 + lg * 8]);

    f32x4 acc0 = {0.f, 0.f, 0.f, 0.f}, acc1 = acc0, acc2 = acc0, acc3 = acc0;
#pragma unroll
    for (int kk = 0; kk < 8; ++kk) {
        acc0 = __builtin_amdgcn_mfma_f32_16x16x32_bf16(a[kk], b0[kk],  acc0, 0, 0, 0);
        acc1 = __builtin_amdgcn_mfma_f32_16x16x32_bf16(a[kk], b1f[kk], acc1, 0, 0, 0);
        acc2 = __builtin_amdgcn_mfma_f32_16x16x32_bf16(a[kk], b2f[kk], acc2, 0, 0, 0);
        acc3 = __builtin_amdgcn_mfma_f32_16x16x32_bf16(a[kk], b3f[kk], acc3, 0, 0, 0);
    }

    // store h2 rows m0 + lg*4 + j, cols nt*16 + lr
#pragma unroll
    for (int j = 0; j < 4; ++j) {
        float* hr = &h2[(size_t)(m0 + lg * 4 + j) * 64];
        hr[0 * 16 + lr] = acc0[j];
        hr[1 * 16 + lr] = acc1[j];
        hr[2 * 16 + lr] = acc2[j];
        hr[3 * 16 + lr] = acc3[j];
    }

    // fused al_s2/al_d2: row r = lg*4 + j
    float sA0 = a_src2[0 * 16 + lr], sA1 = a_src2[1 * 16 + lr];
    float sA2 = a_src2[2 * 16 + lr], sA3 = a_src2[3 * 16 + lr];
    float sD0 = a_dst2[0 * 16 + lr], sD1 = a_dst2[1 * 16 + lr];
    float sD2 = a_dst2[2 * 16 + lr], sD3 = a_dst2[3 * 16 + lr];
    float p0 = acc0[0] * sA0 + acc1[0] * sA1 + acc2[0] * sA2 + acc3[0] * sA3;
    float p1 = acc0[1] * sA0 + acc1[1] * sA1 + acc2[1] * sA2 + acc3[1] * sA3;
    float p2 = acc0[2] * sA0 + acc1[2] * sA1 + acc2[2] * sA2 + acc3[2] * sA3;
    float p3 = acc0[3] * sA0 + acc1[3] * sA1 + acc2[3] * sA2 + acc3[3] * sA3;
    float q0 = acc0[0] * sD0 + acc1[0] * sD1 + acc2[0] * sD2 + acc3[0] * sD3;
    float q1 = acc0[1] * sD0 + acc1[1] * sD1 + acc2[1] * sD2 + acc3[1] * sD3;
    float q2 = acc0[2] * sD0 + acc1[2] * sD1 + acc2[2] * sD2 + acc3[2] * sD3;
    float q3 = acc0[3] * sD0 + acc1[3] * sD1 + acc2[3] * sD2 + acc3[3] * sD3;
#pragma unroll
    for (int off = 1; off <= 8; off <<= 1) {   // reduce within 16-lane group
        p0 += __shfl_xor(p0, off, 64); p1 += __shfl_xor(p1, off, 64);
        p2 += __shfl_xor(p2, off, 64); p3 += __shfl_xor(p3, off, 64);
        q0 += __shfl_xor(q0, off, 64); q1 += __shfl_xor(q1, off, 64);
        q2 += __shfl_xor(q2, off, 64); q3 += __shfl_xor(q3, off, 64);
    }
    if (lr == 0) {
        int r0 = m0 + lg * 4;
        al_s2[r0 + 0] = p0; al_s2[r0 + 1] = p1; al_s2[r0 + 2] = p2; al_s2[r0 + 3] = p3;
        al_d2[r0 + 0] = q0; al_d2[r0 + 1] = q1; al_d2[r0 + 2] = q2; al_d2[r0 + 3] = q3;
    }
}

// ---------------------------------------------------------------------------
// K4': layer-2 aggregation, gather-style. One wave per dst; lane = channel.
// ---------------------------------------------------------------------------
__global__ __launch_bounds__(256) void k4_gather2(
    const int* __restrict__ csr_src, const int* __restrict__ row_ptr,
    const float* __restrict__ h2, const float* __restrict__ al_s2,
    const float* __restrict__ al_d2, float* __restrict__ o2, int N) {
    int wave = threadIdx.x >> 6, lane = threadIdx.x & 63;
    int n = blockIdx.x * 4 + wave;
    if (n >= N) return;
    int beg = row_ptr[n], end = row_ptr[n + 1];
    float ad = al_d2[n];
    float a = 0.f, d = 0.f;
    for (int base = beg; base < end; base += 64) {
        int nn = min(64, end - base);
        bool ok = (base + lane < end);
        int srcv = ok ? csr_src[base + lane] : 0;
        float asv = ok ? al_s2[srcv] : 0.f;
        for (int i = 0; i < nn; ++i) {
            int src = __shfl(srcv, i, 64);
            float as = __shfl(asv, i, 64);
            float v = as + ad;
            v = v > 0.f ? v : NEG_SLOPE * v;
            float ex = __expf(v);
            a = fmaf(ex, h2[(size_t)src * 64 + lane], a);
            d += ex;
        }
    }
    o2[(size_t)n * 64 + lane] = a / d;
}

// ---------------------------------------------------------------------------
// K5: node-mean + bias. Block = 1 wave, grid-stride over nodes.
// ---------------------------------------------------------------------------
__global__ __launch_bounds__(64) void k5_final(
    const float* __restrict__ o2, const float* __restrict__ b2,
    float* __restrict__ out, int N) {
    int lane = threadIdx.x;
    float acc = 0.f;
    for (int n = blockIdx.x; n < N; n += gridDim.x)
        acc += o2[(size_t)n * 64 + lane];
    float v = acc * (1.f / (float)N);
    if (blockIdx.x == 0) v += b2[lane];
    atomicAdd(&out[lane], v);
}

extern "C" void kernel_launch(void* const* d_in, const int* in_sizes, int n_in,
                              void* d_out, int out_size, void* d_ws, size_t ws_size,
                              hipStream_t stream) {
    const float* x   = (const float*)d_in[0];
    const int*   ei  = (const int*)d_in[1];
    const float* W1  = (const float*)d_in[2];
    const float* as1 = (const float*)d_in[3];
    const float* ad1 = (const float*)d_in[4];
    const float* b1  = (const float*)d_in[5];
    const float* W2  = (const float*)d_in[6];
    const float* as2 = (const float*)d_in[7];
    const float* ad2 = (const float*)d_in[8];
    const float* b2  = (const float*)d_in[9];
    float* out = (float*)d_out;

    const int F_in = in_sizes[2] / 256;        // W1: [F_in, 4*64]
    const int N = in_sizes[0] / F_in;
    const int E = in_sizes[1] / 2;
    const int Etot = E + N;

    // Workspace (~70 MB). Aliases: o2 = h1b (dead after K2);
    // al_s2/al_d2 = al_s1/al_d1 (dead after K2).
    unsigned short* h1b = (unsigned short*)d_ws;        // N*256 us
    unsigned short* x2b = h1b + (size_t)N * 256;        // N*256 us
    float* h2    = (float*)(x2b + (size_t)N * 256);     // N*64 f32
    float* al_s1 = h2 + (size_t)N * 64;                 // N*4
    float* al_d1 = al_s1 + (size_t)N * 4;               // N*4
    unsigned short* W2t = (unsigned short*)(al_d1 + (size_t)N * 4);  // 64*256 us
    int* deg     = (int*)(W2t + 64 * 256);              // N
    int* row_cur = deg + N;                             // N
    int* row_ptr = row_cur + N;                         // N+1
    int* csr_src = row_ptr + N + 1;                     // Etot
    float* o2    = (float*)h1b;                         // alias, N*64 f32
    float* al_s2 = al_s1;                               // alias
    float* al_d2 = al_d1;                               // alias

    hipMemsetAsync(deg, 0, (size_t)N * sizeof(int), stream);
    hipMemsetAsync(out, 0, 64 * sizeof(float), stream);

    kb1_deg    <<<(Etot + 255) / 256, 256, 0, stream>>>(ei, E, Etot, deg);
    kb2_scan   <<<1, 1024, 0, stream>>>(deg, N, Etot, row_ptr, row_cur);
    kb3_scatter<<<(Etot + 255) / 256, 256, 0, stream>>>(ei, E, Etot, row_cur, csr_src);
    kw_pack    <<<64, 256, 0, stream>>>(W2, W2t);

    k1_node1  <<<N, 256, 0, stream>>>(x, W1, as1, ad1, h1b, al_s1, al_d1, N);
    k2_gather1<<<(N + 3) / 4, 256, 0, stream>>>(csr_src, row_ptr, h1b, al_s1, al_d1, b1, x2b, N);
    k3_mfma   <<<(N + 63) / 64, 256, 0, stream>>>(x2b, W2t, as2, ad2, h2, al_s2, al_d2, N);
    k4_gather2<<<(N + 3) / 4, 256, 0, stream>>>(csr_src, row_ptr, h2, al_s2, al_d2, o2, N);
    k5_final  <<<256, 64, 0, stream>>>(o2, b2, out, N);
}

// Round 9
// 426.429 us; speedup vs baseline: 3.2159x; 1.2160x over previous
//
#include <hip/hip_runtime.h>
#include <hip/hip_bf16.h>

#define NEG_SLOPE 0.2f

typedef __attribute__((ext_vector_type(8))) short short8;   // 8 bf16 (4 VGPRs)
typedef __attribute__((ext_vector_type(4))) float f32x4;

__device__ __forceinline__ float wave_sum64(float v) {
#pragma unroll
    for (int off = 32; off >= 1; off >>= 1) v += __shfl_xor(v, off, 64);
    return v;
}

__device__ __forceinline__ float bf2f(unsigned short u) {
    return __uint_as_float((unsigned int)u << 16);
}

__device__ __forceinline__ unsigned short f2bf(float f) {
    __hip_bfloat16 hb = __float2bfloat16(f);   // RNE
    return *reinterpret_cast<unsigned short*>(&hb);
}

// ---------------------------------------------------------------------------
// CSR build: KB1 degree histogram -> KB2 unordered segment allocation
// (per-wave shfl scan + ONE atomicAdd per wave; segment ORDER is irrelevant,
// only disjointness matters) -> KB3 scatter.
// ---------------------------------------------------------------------------
__global__ __launch_bounds__(256) void kb1_deg(
    const int* __restrict__ ei, int E, int Etot, int* __restrict__ deg) {
    int e = blockIdx.x * 256 + threadIdx.x;
    if (e >= Etot) return;
    int dst = (e < E) ? ei[E + e] : e - E;   // self-loops appended
    atomicAdd(&deg[dst], 1);
}

__global__ __launch_bounds__(256) void kb2_alloc(
    const int* __restrict__ deg, int N, int* __restrict__ counter,
    int* __restrict__ row_ptr, int* __restrict__ row_end,
    int* __restrict__ row_cur) {
    int n = blockIdx.x * 256 + threadIdx.x;
    int lane = threadIdx.x & 63;
    int d = (n < N) ? deg[n] : 0;
    int x = d;                                   // inclusive wave scan
#pragma unroll
    for (int off = 1; off < 64; off <<= 1) {
        int y = __shfl_up(x, off, 64);
        if (lane >= off) x += y;
    }
    int total = __shfl(x, 63, 64);
    int base = 0;
    if (lane == 63) base = atomicAdd(counter, total);
    base = __shfl(base, 63, 64);
    if (n < N) {
        int beg = base + x - d;
        row_ptr[n] = beg; row_cur[n] = beg; row_end[n] = beg + d;
    }
}

__global__ __launch_bounds__(256) void kb3_scatter(
    const int* __restrict__ ei, int E, int Etot,
    int* __restrict__ row_cur, int* __restrict__ csr_src) {
    int e = blockIdx.x * 256 + threadIdx.x;
    if (e >= Etot) return;
    int src, dst;
    if (e < E) { src = ei[e]; dst = ei[E + e]; }
    else       { src = dst = e - E; }
    int pos = atomicAdd(&row_cur[dst], 1);
    csr_src[pos] = src;
}

// ---------------------------------------------------------------------------
// KW: pack W2 [256,64] f32 -> W2t [64 cols][256 k] bf16 (B-fragment friendly:
// contiguous k per col). 16384 elements, one-shot.
// ---------------------------------------------------------------------------
__global__ __launch_bounds__(256) void kw_pack(
    const float* __restrict__ W2, unsigned short* __restrict__ W2t) {
    int i = blockIdx.x * 256 + threadIdx.x;   // grid 64 blocks
    if (i >= 64 * 256) return;
    int c = i >> 8, k = i & 255;
    W2t[c * 256 + k] = f2bf(W2[k * 64 + c]);
}

// ---------------------------------------------------------------------------
// K1: layer-1 node transform. One block (256 thr) per node.
// h in fp32 (exact al_s/al_d); h1 stored bf16 head-interleaved
// h1b[n*256 + ch*4 + head] so K2's lane reads 4 head-values as one 8B load.
// ---------------------------------------------------------------------------
__global__ __launch_bounds__(256) void k1_node1(
    const float* __restrict__ x, const float* __restrict__ W1,
    const float* __restrict__ a_src1, const float* __restrict__ a_dst1,
    unsigned short* __restrict__ h1b, float* __restrict__ al_s1,
    float* __restrict__ al_d1, int N) {
    int n = blockIdx.x;
    if (n >= N) return;
    int t = threadIdx.x;
    float h = 0.f;
#pragma unroll
    for (int k = 0; k < 5; ++k) h = fmaf(x[n * 5 + k], W1[k * 256 + t], h);
    int head = t >> 6, ch = t & 63;
    h1b[(size_t)n * 256 + ch * 4 + head] = f2bf(h);
    float s = wave_sum64(h * a_src1[t]);
    float d = wave_sum64(h * a_dst1[t]);
    if (ch == 0) {
        al_s1[n * 4 + head] = s;
        al_d1[n * 4 + head] = d;
    }
}

// ---------------------------------------------------------------------------
// K2': layer-1 aggregation, gather-style. One wave per dst node; lane = ch.
// Per edge: one 8B load of 4 bf16 head-values + one 16B al_s1 load.
// Epilogue fuses softmax-normalize + b1 + relu -> writes x2b (bf16, layer-2
// GEMM A-operand). Softmax max-shift elided (exact; logits O(1)).
// ---------------------------------------------------------------------------
__global__ __launch_bounds__(256) void k2_gather1(
    const int* __restrict__ csr_src, const int* __restrict__ row_ptr,
    const int* __restrict__ row_end,
    const unsigned short* __restrict__ h1b, const float* __restrict__ al_s1,
    const float* __restrict__ al_d1, const float* __restrict__ b1,
    unsigned short* __restrict__ x2b, int N) {
    int wave = threadIdx.x >> 6, lane = threadIdx.x & 63;
    int n = blockIdx.x * 4 + wave;
    if (n >= N) return;
    int beg = row_ptr[n], end = row_end[n];
    const float4 ad = *reinterpret_cast<const float4*>(&al_d1[n * 4]);
    float a0 = 0.f, a1 = 0.f, a2 = 0.f, a3 = 0.f;
    float d0 = 0.f, d1 = 0.f, d2 = 0.f, d3 = 0.f;
    for (int base = beg; base < end; base += 64) {
        int nn = min(64, end - base);
        int srcv = (base + lane < end) ? csr_src[base + lane] : 0;
        for (int i = 0; i < nn; ++i) {
            int src = __shfl(srcv, i, 64);
            const float4 as = *reinterpret_cast<const float4*>(&al_s1[src * 4]);
            float v0 = as.x + ad.x, v1 = as.y + ad.y, v2 = as.z + ad.z, v3 = as.w + ad.w;
            v0 = v0 > 0.f ? v0 : NEG_SLOPE * v0;
            v1 = v1 > 0.f ? v1 : NEG_SLOPE * v1;
            v2 = v2 > 0.f ? v2 : NEG_SLOPE * v2;
            v3 = v3 > 0.f ? v3 : NEG_SLOPE * v3;
            float ex0 = __expf(v0), ex1 = __expf(v1), ex2 = __expf(v2), ex3 = __expf(v3);
            const ushort4 u = *reinterpret_cast<const ushort4*>(
                &h1b[(size_t)src * 256 + lane * 4]);
            a0 = fmaf(ex0, bf2f(u.x), a0); d0 += ex0;
            a1 = fmaf(ex1, bf2f(u.y), a1); d1 += ex1;
            a2 = fmaf(ex2, bf2f(u.z), a2); d2 += ex2;
            a3 = fmaf(ex3, bf2f(u.w), a3); d3 += ex3;
        }
    }
    unsigned short* xo = &x2b[(size_t)n * 256];
    float r;
    r = a0 / d0 + b1[0 * 64 + lane]; xo[0 * 64 + lane] = f2bf(r > 0.f ? r : 0.f);
    r = a1 / d1 + b1[1 * 64 + lane]; xo[1 * 64 + lane] = f2bf(r > 0.f ? r : 0.f);
    r = a2 / d2 + b1[2 * 64 + lane]; xo[2 * 64 + lane] = f2bf(r > 0.f ? r : 0.f);
    r = a3 / d3 + b1[3 * 64 + lane]; xo[3 * 64 + lane] = f2bf(r > 0.f ? r : 0.f);
}

// ---------------------------------------------------------------------------
// K3 (MFMA): h2 = x2b @ W2, [N,256]@[256,64] bf16->f32.
// Block = 4 waves = 64 rows; wave = 16-row M-tile, 4 N-tiles of 16 cols,
// K=256 in 8 steps of 32 via mfma_f32_16x16x32_bf16.
// A frag: lane l -> row l&15, k=(l>>4)*8+j (row-major x2b, one 16B load).
// B frag: lane l -> col l&15, same k (col-major W2t, one 16B load).
// D: col=lane&15, row=(lane>>4)*4+reg [m89].
// al_s2/al_d2 fused: per-lane partials + 16-lane shfl_xor reduce.
// ---------------------------------------------------------------------------
__global__ __launch_bounds__(256) void k3_mfma(
    const unsigned short* __restrict__ x2b, const unsigned short* __restrict__ W2t,
    const float* __restrict__ a_src2, const float* __restrict__ a_dst2,
    float* __restrict__ h2, float* __restrict__ al_s2, float* __restrict__ al_d2,
    int N) {
    int w = threadIdx.x >> 6, l = threadIdx.x & 63;
    int m0 = blockIdx.x * 64 + w * 16;
    if (m0 >= N) return;
    int lr = l & 15, lg = l >> 4;

    short8 b0[8], b1f[8], b2f[8], b3f[8];   // full W2 in regs (128 VGPR)
#pragma unroll
    for (int kk = 0; kk < 8; ++kk) {
        b0[kk]  = *reinterpret_cast<const short8*>(&W2t[(0 * 16 + lr) * 256 + kk * 32 + lg * 8]);
        b1f[kk] = *reinterpret_cast<const short8*>(&W2t[(1 * 16 + lr) * 256 + kk * 32 + lg * 8]);
        b2f[kk] = *reinterpret_cast<const short8*>(&W2t[(2 * 16 + lr) * 256 + kk * 32 + lg * 8]);
        b3f[kk] = *reinterpret_cast<const short8*>(&W2t[(3 * 16 + lr) * 256 + kk * 32 + lg * 8]);
    }
    short8 a[8];
#pragma unroll
    for (int kk = 0; kk < 8; ++kk)
        a[kk] = *reinterpret_cast<const short8*>(&x2b[(size_t)(m0 + lr) * 256 + kk * 32 + lg * 8]);

    f32x4 acc0 = {0.f, 0.f, 0.f, 0.f}, acc1 = acc0, acc2 = acc0, acc3 = acc0;
#pragma unroll
    for (int kk = 0; kk < 8; ++kk) {
        acc0 = __builtin_amdgcn_mfma_f32_16x16x32_bf16(a[kk], b0[kk],  acc0, 0, 0, 0);
        acc1 = __builtin_amdgcn_mfma_f32_16x16x32_bf16(a[kk], b1f[kk], acc1, 0, 0, 0);
        acc2 = __builtin_amdgcn_mfma_f32_16x16x32_bf16(a[kk], b2f[kk], acc2, 0, 0, 0);
        acc3 = __builtin_amdgcn_mfma_f32_16x16x32_bf16(a[kk], b3f[kk], acc3, 0, 0, 0);
    }

    // store h2 rows m0 + lg*4 + j, cols nt*16 + lr
#pragma unroll
    for (int j = 0; j < 4; ++j) {
        float* hr = &h2[(size_t)(m0 + lg * 4 + j) * 64];
        hr[0 * 16 + lr] = acc0[j];
        hr[1 * 16 + lr] = acc1[j];
        hr[2 * 16 + lr] = acc2[j];
        hr[3 * 16 + lr] = acc3[j];
    }

    // fused al_s2/al_d2: row r = lg*4 + j
    float sA0 = a_src2[0 * 16 + lr], sA1 = a_src2[1 * 16 + lr];
    float sA2 = a_src2[2 * 16 + lr], sA3 = a_src2[3 * 16 + lr];
    float sD0 = a_dst2[0 * 16 + lr], sD1 = a_dst2[1 * 16 + lr];
    float sD2 = a_dst2[2 * 16 + lr], sD3 = a_dst2[3 * 16 + lr];
    float p0 = acc0[0] * sA0 + acc1[0] * sA1 + acc2[0] * sA2 + acc3[0] * sA3;
    float p1 = acc0[1] * sA0 + acc1[1] * sA1 + acc2[1] * sA2 + acc3[1] * sA3;
    float p2 = acc0[2] * sA0 + acc1[2] * sA1 + acc2[2] * sA2 + acc3[2] * sA3;
    float p3 = acc0[3] * sA0 + acc1[3] * sA1 + acc2[3] * sA2 + acc3[3] * sA3;
    float q0 = acc0[0] * sD0 + acc1[0] * sD1 + acc2[0] * sD2 + acc3[0] * sD3;
    float q1 = acc0[1] * sD0 + acc1[1] * sD1 + acc2[1] * sD2 + acc3[1] * sD3;
    float q2 = acc0[2] * sD0 + acc1[2] * sD1 + acc2[2] * sD2 + acc3[2] * sD3;
    float q3 = acc0[3] * sD0 + acc1[3] * sD1 + acc2[3] * sD2 + acc3[3] * sD3;
#pragma unroll
    for (int off = 1; off <= 8; off <<= 1) {   // reduce within 16-lane group
        p0 += __shfl_xor(p0, off, 64); p1 += __shfl_xor(p1, off, 64);
        p2 += __shfl_xor(p2, off, 64); p3 += __shfl_xor(p3, off, 64);
        q0 += __shfl_xor(q0, off, 64); q1 += __shfl_xor(q1, off, 64);
        q2 += __shfl_xor(q2, off, 64); q3 += __shfl_xor(q3, off, 64);
    }
    if (lr == 0) {
        int r0 = m0 + lg * 4;
        al_s2[r0 + 0] = p0; al_s2[r0 + 1] = p1; al_s2[r0 + 2] = p2; al_s2[r0 + 3] = p3;
        al_d2[r0 + 0] = q0; al_d2[r0 + 1] = q1; al_d2[r0 + 2] = q2; al_d2[r0 + 3] = q3;
    }
}

// ---------------------------------------------------------------------------
// K4': layer-2 aggregation, gather-style. One wave per dst; lane = channel.
// ---------------------------------------------------------------------------
__global__ __launch_bounds__(256) void k4_gather2(
    const int* __restrict__ csr_src, const int* __restrict__ row_ptr,
    const int* __restrict__ row_end,
    const float* __restrict__ h2, const float* __restrict__ al_s2,
    const float* __restrict__ al_d2, float* __restrict__ o2, int N) {
    int wave = threadIdx.x >> 6, lane = threadIdx.x & 63;
    int n = blockIdx.x * 4 + wave;
    if (n >= N) return;
    int beg = row_ptr[n], end = row_end[n];
    float ad = al_d2[n];
    float a = 0.f, d = 0.f;
    for (int base = beg; base < end; base += 64) {
        int nn = min(64, end - base);
        bool ok = (base + lane < end);
        int srcv = ok ? csr_src[base + lane] : 0;
        float asv = ok ? al_s2[srcv] : 0.f;
        for (int i = 0; i < nn; ++i) {
            int src = __shfl(srcv, i, 64);
            float as = __shfl(asv, i, 64);
            float v = as + ad;
            v = v > 0.f ? v : NEG_SLOPE * v;
            float ex = __expf(v);
            a = fmaf(ex, h2[(size_t)src * 64 + lane], a);
            d += ex;
        }
    }
    o2[(size_t)n * 64 + lane] = a / d;
}

// ---------------------------------------------------------------------------
// K5: node-mean + bias. Block = 1 wave, grid-stride over nodes.
// ---------------------------------------------------------------------------
__global__ __launch_bounds__(64) void k5_final(
    const float* __restrict__ o2, const float* __restrict__ b2,
    float* __restrict__ out, int N) {
    int lane = threadIdx.x;
    float acc = 0.f;
    for (int n = blockIdx.x; n < N; n += gridDim.x)
        acc += o2[(size_t)n * 64 + lane];
    float v = acc * (1.f / (float)N);
    if (blockIdx.x == 0) v += b2[lane];
    atomicAdd(&out[lane], v);
}

extern "C" void kernel_launch(void* const* d_in, const int* in_sizes, int n_in,
                              void* d_out, int out_size, void* d_ws, size_t ws_size,
                              hipStream_t stream) {
    const float* x   = (const float*)d_in[0];
    const int*   ei  = (const int*)d_in[1];
    const float* W1  = (const float*)d_in[2];
    const float* as1 = (const float*)d_in[3];
    const float* ad1 = (const float*)d_in[4];
    const float* b1  = (const float*)d_in[5];
    const float* W2  = (const float*)d_in[6];
    const float* as2 = (const float*)d_in[7];
    const float* ad2 = (const float*)d_in[8];
    const float* b2  = (const float*)d_in[9];
    float* out = (float*)d_out;

    const int F_in = in_sizes[2] / 256;        // W1: [F_in, 4*64]
    const int N = in_sizes[0] / F_in;
    const int E = in_sizes[1] / 2;
    const int Etot = E + N;

    // Workspace (~70 MB). Aliases: o2 = h1b (dead after K2);
    // al_s2/al_d2 = al_s1/al_d1 (dead after K2).
    unsigned short* h1b = (unsigned short*)d_ws;        // N*256 us
    unsigned short* x2b = h1b + (size_t)N * 256;        // N*256 us
    float* h2    = (float*)(x2b + (size_t)N * 256);     // N*64 f32
    float* al_s1 = h2 + (size_t)N * 64;                 // N*4
    float* al_d1 = al_s1 + (size_t)N * 4;               // N*4
    unsigned short* W2t = (unsigned short*)(al_d1 + (size_t)N * 4);  // 64*256 us
    int* deg     = (int*)(W2t + 64 * 256);              // N
    int* row_cur = deg + N;                             // N
    int* row_ptr = row_cur + N;                         // N
    int* row_end = row_ptr + N;                         // N
    int* counter = row_end + N;                         // 1
    int* csr_src = counter + 1;                         // Etot
    float* o2    = (float*)h1b;                         // alias, N*64 f32
    float* al_s2 = al_s1;                               // alias
    float* al_d2 = al_d1;                               // alias

    hipMemsetAsync(deg, 0, (size_t)N * sizeof(int), stream);
    hipMemsetAsync(counter, 0, sizeof(int), stream);
    hipMemsetAsync(out, 0, 64 * sizeof(float), stream);

    kb1_deg    <<<(Etot + 255) / 256, 256, 0, stream>>>(ei, E, Etot, deg);
    kb2_alloc  <<<(N + 255) / 256, 256, 0, stream>>>(deg, N, counter, row_ptr, row_end, row_cur);
    kb3_scatter<<<(Etot + 255) / 256, 256, 0, stream>>>(ei, E, Etot, row_cur, csr_src);
    kw_pack    <<<64, 256, 0, stream>>>(W2, W2t);

    k1_node1  <<<N, 256, 0, stream>>>(x, W1, as1, ad1, h1b, al_s1, al_d1, N);
    k2_gather1<<<(N + 3) / 4, 256, 0, stream>>>(csr_src, row_ptr, row_end, h1b, al_s1, al_d1, b1, x2b, N);
    k3_mfma   <<<(N + 63) / 64, 256, 0, stream>>>(x2b, W2t, as2, ad2, h2, al_s2, al_d2, N);
    k4_gather2<<<(N + 3) / 4, 256, 0, stream>>>(csr_src, row_ptr, row_end, h2, al_s2, al_d2, o2, N);
    k5_final  <<<256, 64, 0, stream>>>(o2, b2, out, N);
}